// Round 11
// baseline (2904.442 us; speedup 1.0000x reference)
//
#include <hip/hip_runtime.h>
#include <hip/hip_cooperative_groups.h>
#include <math.h>

namespace cg = cooperative_groups;

#define Bc   2
#define Hc   240
#define Wc   1216
#define CHG  64
#define HWc  (Hc*Wc)          // 291840
#define NPIX (Bc*HWc)         // 583680
#define QTR  (NPIX/4)         // 145920

// d_out layout (floats): [feat NPIX][offset 2*18*HW][aff 9*HW]
#define OUT1 (NPIX)
#define OUT2 (OUT1 + Bc*18*HWc)

// ws layout (floats): wr[13824] | buf0[NPIX] | buf1[NPIX]
#define WS_WR    0
#define WS_BUF0  (13824)
#define WS_BUF1  (WS_BUF0 + NPIX)

// zero-padded bilinear sample from a (Hc,Wc) plane
__device__ __forceinline__ float bilin(const float* __restrict__ f, float ys, float xs) {
    float y0f = floorf(ys), x0f = floorf(xs);
    float wy1 = ys - y0f,   wx1 = xs - x0f;
    float wy0 = 1.f - wy1,  wx0 = 1.f - wx1;
    int y0 = (int)y0f, x0 = (int)x0f;
    int y1 = y0 + 1,   x1 = x0 + 1;
    int y0c = min(max(y0, 0), Hc-1), y1c = min(max(y1, 0), Hc-1);
    int x0c = min(max(x0, 0), Wc-1), x1c = min(max(x1, 0), Wc-1);
    float my0 = (y0 >= 0 && y0 < Hc) ? 1.f : 0.f;
    float my1 = (y1 >= 0 && y1 < Hc) ? 1.f : 0.f;
    float mx0 = (x0 >= 0 && x0 < Wc) ? 1.f : 0.f;
    float mx1 = (x1 >= 0 && x1 < Wc) ? 1.f : 0.f;
    float v00 = f[y0c*Wc + x0c] * (my0*mx0);
    float v01 = f[y0c*Wc + x1c] * (my0*mx1);
    float v10 = f[y1c*Wc + x0c] * (my1*mx0);
    float v11 = f[y1c*Wc + x1c] * (my1*mx1);
    return wy0*(wx0*v00 + wx1*v01) + wy1*(wx0*v10 + wx1*v11);
}

// reorder w_oa (24,64,3,3) -> wr[(c*9+j)*24 + oc]
__global__ void reorder_w(const float* __restrict__ w_oa, float* __restrict__ wr) {
    int i = blockIdx.x*256 + threadIdx.x;   // over 24*576
    if (i < 24*576) {
        int oc = i / 576; int cj = i - oc*576;
        wr[cj*24 + oc] = w_oa[i];
    }
}

// fused: 3x3 conv (64->24) + offset/aff epilogue + init masked feat buffer
// (round-2 proven version: 68 VGPR, ~261 us)
__global__ __launch_bounds__(256) void conv_epilogue(
    const float* __restrict__ guid, const float* __restrict__ conf,
    const float* __restrict__ wr,   const float* __restrict__ b_oa,
    const float* __restrict__ aff_scale,
    const float* __restrict__ feat_init, const float* __restrict__ feat_fix,
    float* __restrict__ dout, float* __restrict__ buf0)
{
    int p  = blockIdx.x*256 + threadIdx.x;
    int b  = p / HWc;
    int hw = p - b*HWc;
    int h  = hw / Wc;
    int w  = hw - h*Wc;

    int   aoff[9];
    float msk[9];
    #pragma unroll
    for (int dy = 0; dy < 3; ++dy) {
        int hy = h + dy - 1;
        float my = (hy >= 0 && hy < Hc) ? 1.f : 0.f;
        int hyc = min(max(hy, 0), Hc-1);
        #pragma unroll
        for (int dx = 0; dx < 3; ++dx) {
            int wx = w + dx - 1;
            float mx = (wx >= 0 && wx < Wc) ? 1.f : 0.f;
            int wxc = min(max(wx, 0), Wc-1);
            aoff[dy*3+dx] = hyc*Wc + wxc;
            msk [dy*3+dx] = my*mx;
        }
    }

    float acc[24];
    #pragma unroll
    for (int oc = 0; oc < 24; ++oc) acc[oc] = b_oa[oc];

    const float* gb = guid + (size_t)b*CHG*HWc;
    for (int c = 0; c < CHG; ++c) {
        const float* gc = gb + c*HWc;
        #pragma unroll
        for (int j = 0; j < 9; ++j) {
            float g = gc[aoff[j]] * msk[j];
            const float* wp = wr + (c*9 + j)*24;   // wave-uniform -> s_load
            #pragma unroll
            for (int oc = 0; oc < 24; ++oc)
                acc[oc] = fmaf(g, wp[oc], acc[oc]);
        }
    }

    // epilogue: tap k -> (acc[2k], acc[2k+1]); aff raw acc[16+k]
    float scale = 1.f / (aff_scale[0] + 1e-8f);
    const float* cb = conf + (size_t)b*HWc;
    float oyv[8], oxv[8], af[8];
    float ssum = 0.f;
    #pragma unroll
    for (int k = 0; k < 8; ++k) { oyv[k] = acc[2*k]; oxv[k] = acc[2*k+1]; }
    #pragma unroll
    for (int k = 0; k < 8; ++k) {
        float a  = tanhf(acc[16+k]) * scale;
        float ys = (float)h + oyv[k];
        float xs = (float)w + oxv[k];
        a *= bilin(cb, ys, xs);
        af[k] = a;
        ssum += fabsf(a);
    }
    float inv = 1.f / fmaxf(ssum + 1e-4f, 1.f);
    float asum = 0.f;
    #pragma unroll
    for (int k = 0; k < 8; ++k) { af[k] *= inv; asum += af[k]; }
    float aref = 1.f - asum;

    float* ob = dout + OUT1 + (size_t)b*18*HWc + hw;
    float* ab = dout + OUT2 + (size_t)b*9*HWc  + hw;
    #pragma unroll
    for (int kf = 0; kf < 9; ++kf) {
        float oy, ox, av;
        if (kf == 4) { oy = 0.f; ox = 0.f; av = aref; }
        else { int k = (kf < 4) ? kf : kf-1; oy = oyv[k]; ox = oxv[k]; av = af[k]; }
        ob[(size_t)(2*kf  )*HWc] = oy;
        ob[(size_t)(2*kf+1)*HWc] = ox;
        ab[(size_t)kf*HWc]       = av;
    }

    float ffv = feat_fix[p];
    buf0[p] = (ffv > 0.f) ? ffv : feat_init[p];
}

// all 18 propagation steps in one cooperative kernel; taps live in registers
__global__ __launch_bounds__(256, 3) void prop_fused(
    const float* __restrict__ buf0, float* __restrict__ buf1,
    const float* __restrict__ doff, const float* __restrict__ daff,
    const float* __restrict__ feat_fix, float* __restrict__ out)
{
    int t = blockIdx.x*256 + threadIdx.x;   // 0..QTR-1

    float ys[4][8], xs[4][8], af[4][8], a4[4], ff[4];
    int   hwv[4], bof[4];

    #pragma unroll
    for (int i = 0; i < 4; ++i) {
        int p  = t + i*QTR;
        int b  = p / HWc;
        int hw = p - b*HWc;
        int h  = hw / Wc;
        int w  = hw - h*Wc;
        hwv[i] = hw; bof[i] = b*HWc;
        const float* ob = doff + (size_t)b*18*HWc + hw;
        const float* ab = daff + (size_t)b*9*HWc  + hw;
        #pragma unroll
        for (int k = 0; k < 8; ++k) {
            int kf = (k < 4) ? k : k+1;
            float oy = ob[(size_t)(2*kf  )*HWc];
            float ox = ob[(size_t)(2*kf+1)*HWc];
            ys[i][k] = (float)(h + kf/3 - 1) + oy;
            xs[i][k] = (float)(w + kf%3 - 1) + ox;
            af[i][k] = ab[(size_t)kf*HWc];
        }
        a4[i] = ab[(size_t)4*HWc];
        ff[i] = feat_fix[p];
    }

    cg::grid_group grid = cg::this_grid();

    const float* src = buf0;
    float*       dst = buf1;

    #pragma unroll 1
    for (int step = 0; step < 18; ++step) {
        float* wdst = (step == 17) ? out : dst;
        #pragma unroll
        for (int i = 0; i < 4; ++i) {
            const float* fb = src + bof[i];
            float s = a4[i] * fb[hwv[i]];          // exact center tap
            #pragma unroll
            for (int k = 0; k < 8; ++k)
                s += af[i][k] * bilin(fb, ys[i][k], xs[i][k]);
            float o = (step == 17) ? s : ((ff[i] > 0.f) ? ff[i] : s);
            wdst[bof[i] + hwv[i]] = o;
        }
        if (step < 17) grid.sync();
        const float* tmp = src; src = dst; dst = (float*)tmp;
    }
}

// fallback: one propagation step (round-2 proven version)
__global__ __launch_bounds__(256) void prop_step(
    const float* __restrict__ fin,
    const float* __restrict__ doff,
    const float* __restrict__ daff,
    const float* __restrict__ feat_fix,
    float* __restrict__ out, int apply_mask)
{
    int p  = blockIdx.x*256 + threadIdx.x;
    int b  = p / HWc;
    int hw = p - b*HWc;
    int h  = hw / Wc;
    int w  = hw - h*Wc;

    const float* fb = fin  + (size_t)b*HWc;
    const float* ob = doff + (size_t)b*18*HWc + hw;
    const float* ab = daff + (size_t)b*9*HWc  + hw;

    float s = 0.f;
    #pragma unroll
    for (int kf = 0; kf < 9; ++kf) {
        float offy = ob[(size_t)(2*kf  )*HWc];
        float offx = ob[(size_t)(2*kf+1)*HWc];
        float a    = ab[(size_t)kf*HWc];
        float yss = (float)(h + kf/3 - 1) + offy;
        float xss = (float)(w + kf%3 - 1) + offx;
        s += a * bilin(fb, yss, xss);
    }
    if (apply_mask) {
        float ffv = feat_fix[p];
        out[p] = (ffv > 0.f) ? ffv : s;
    } else {
        out[p] = s;
    }
}

extern "C" void kernel_launch(void* const* d_in, const int* in_sizes, int n_in,
                              void* d_out, int out_size, void* d_ws, size_t ws_size,
                              hipStream_t stream) {
    const float* feat_init  = (const float*)d_in[0];
    const float* guidance   = (const float*)d_in[1];
    const float* confidence = (const float*)d_in[2];
    const float* feat_fix   = (const float*)d_in[3];
    const float* w_oa       = (const float*)d_in[4];
    const float* b_oa       = (const float*)d_in[5];
    const float* aff_scale  = (const float*)d_in[6];
    float* out = (float*)d_out;

    float* wsf  = (float*)d_ws;
    float* wr   = wsf + WS_WR;
    float* buf0 = wsf + WS_BUF0;
    float* buf1 = wsf + WS_BUF1;

    reorder_w<<<(24*576 + 255)/256, 256, 0, stream>>>(w_oa, wr);
    conv_epilogue<<<NPIX/256, 256, 0, stream>>>(
        guidance, confidence, wr, b_oa, aff_scale, feat_init, feat_fix, out, buf0);

    const float* doff = out + OUT1;
    const float* daff = out + OUT2;

    const float* a0 = buf0; float* a1 = buf1;
    void* args[6] = { (void*)&a0, (void*)&a1, (void*)&doff, (void*)&daff,
                      (void*)&feat_fix, (void*)&out };
    hipError_t ce = hipLaunchCooperativeKernel((const void*)prop_fused,
                                               dim3(QTR/256), dim3(256),
                                               args, 0, stream);
    if (ce != hipSuccess) {
        // deterministic fallback: 18 regular launches (round-2 proven path)
        float* bufs[2] = {buf0, buf1};
        for (int i = 1; i <= 18; ++i) {
            const float* fi = bufs[(i-1) & 1];
            float* fo = (i == 18) ? out : bufs[i & 1];
            prop_step<<<NPIX/256, 256, 0, stream>>>(fi, doff, daff, feat_fix, fo,
                                                    (i < 18) ? 1 : 0);
        }
    }
}

// Round 12
// 735.257 us; speedup vs baseline: 3.9502x; 3.9502x over previous
//
#include <hip/hip_runtime.h>
#include <math.h>

#define Bc   2
#define Hc   240
#define Wc   1216
#define CHG  64
#define HWc  (Hc*Wc)          // 291840
#define NPIX (Bc*HWc)         // 583680
#define HALFPIX (NPIX/2)      // 291840

// d_out layout (floats): [feat NPIX][offset 2*18*HW][aff 9*HW]
#define OUT1 (NPIX)
#define OUT2 (OUT1 + Bc*18*HWc)

// ws layout (floats): wr[13824] | buf0[NPIX] | buf1[NPIX]
#define WS_WR    0
#define WS_BUF0  (13824)
#define WS_BUF1  (WS_BUF0 + NPIX)

// zero-padded bilinear sample from a (Hc,Wc) plane
__device__ __forceinline__ float bilin(const float* __restrict__ f, float ys, float xs) {
    float y0f = floorf(ys), x0f = floorf(xs);
    float wy1 = ys - y0f,   wx1 = xs - x0f;
    float wy0 = 1.f - wy1,  wx0 = 1.f - wx1;
    int y0 = (int)y0f, x0 = (int)x0f;
    int y1 = y0 + 1,   x1 = x0 + 1;
    int y0c = min(max(y0, 0), Hc-1), y1c = min(max(y1, 0), Hc-1);
    int x0c = min(max(x0, 0), Wc-1), x1c = min(max(x1, 0), Wc-1);
    float my0 = (y0 >= 0 && y0 < Hc) ? 1.f : 0.f;
    float my1 = (y1 >= 0 && y1 < Hc) ? 1.f : 0.f;
    float mx0 = (x0 >= 0 && x0 < Wc) ? 1.f : 0.f;
    float mx1 = (x1 >= 0 && x1 < Wc) ? 1.f : 0.f;
    float v00 = f[y0c*Wc + x0c] * (my0*mx0);
    float v01 = f[y0c*Wc + x1c] * (my0*mx1);
    float v10 = f[y1c*Wc + x0c] * (my1*mx0);
    float v11 = f[y1c*Wc + x1c] * (my1*mx1);
    return wy0*(wx0*v00 + wx1*v01) + wy1*(wx0*v10 + wx1*v11);
}

// reorder w_oa (24,64,3,3) -> wr[(c*9+j)*24 + oc]
__global__ void reorder_w(const float* __restrict__ w_oa, float* __restrict__ wr) {
    int i = blockIdx.x*256 + threadIdx.x;   // over 24*576
    if (i < 24*576) {
        int oc = i / 576; int cj = i - oc*576;
        wr[cj*24 + oc] = w_oa[i];
    }
}

// fused: 3x3 conv (64->24) + offset/aff epilogue + init masked feat buffer
// (round-2 proven version: 68 VGPR, ~261 us)
__global__ __launch_bounds__(256) void conv_epilogue(
    const float* __restrict__ guid, const float* __restrict__ conf,
    const float* __restrict__ wr,   const float* __restrict__ b_oa,
    const float* __restrict__ aff_scale,
    const float* __restrict__ feat_init, const float* __restrict__ feat_fix,
    float* __restrict__ dout, float* __restrict__ buf0)
{
    int p  = blockIdx.x*256 + threadIdx.x;
    int b  = p / HWc;
    int hw = p - b*HWc;
    int h  = hw / Wc;
    int w  = hw - h*Wc;

    int   aoff[9];
    float msk[9];
    #pragma unroll
    for (int dy = 0; dy < 3; ++dy) {
        int hy = h + dy - 1;
        float my = (hy >= 0 && hy < Hc) ? 1.f : 0.f;
        int hyc = min(max(hy, 0), Hc-1);
        #pragma unroll
        for (int dx = 0; dx < 3; ++dx) {
            int wx = w + dx - 1;
            float mx = (wx >= 0 && wx < Wc) ? 1.f : 0.f;
            int wxc = min(max(wx, 0), Wc-1);
            aoff[dy*3+dx] = hyc*Wc + wxc;
            msk [dy*3+dx] = my*mx;
        }
    }

    float acc[24];
    #pragma unroll
    for (int oc = 0; oc < 24; ++oc) acc[oc] = b_oa[oc];

    const float* gb = guid + (size_t)b*CHG*HWc;
    for (int c = 0; c < CHG; ++c) {
        const float* gc = gb + c*HWc;
        #pragma unroll
        for (int j = 0; j < 9; ++j) {
            float g = gc[aoff[j]] * msk[j];
            const float* wp = wr + (c*9 + j)*24;   // wave-uniform -> s_load
            #pragma unroll
            for (int oc = 0; oc < 24; ++oc)
                acc[oc] = fmaf(g, wp[oc], acc[oc]);
        }
    }

    // epilogue: tap k -> (acc[2k], acc[2k+1]); aff raw acc[16+k]
    float scale = 1.f / (aff_scale[0] + 1e-8f);
    const float* cb = conf + (size_t)b*HWc;
    float oyv[8], oxv[8], af[8];
    float ssum = 0.f;
    #pragma unroll
    for (int k = 0; k < 8; ++k) { oyv[k] = acc[2*k]; oxv[k] = acc[2*k+1]; }
    #pragma unroll
    for (int k = 0; k < 8; ++k) {
        float a  = tanhf(acc[16+k]) * scale;
        float ys = (float)h + oyv[k];
        float xs = (float)w + oxv[k];
        a *= bilin(cb, ys, xs);
        af[k] = a;
        ssum += fabsf(a);
    }
    float inv = 1.f / fmaxf(ssum + 1e-4f, 1.f);
    float asum = 0.f;
    #pragma unroll
    for (int k = 0; k < 8; ++k) { af[k] *= inv; asum += af[k]; }
    float aref = 1.f - asum;

    float* ob = dout + OUT1 + (size_t)b*18*HWc + hw;
    float* ab = dout + OUT2 + (size_t)b*9*HWc  + hw;
    #pragma unroll
    for (int kf = 0; kf < 9; ++kf) {
        float oy, ox, av;
        if (kf == 4) { oy = 0.f; ox = 0.f; av = aref; }
        else { int k = (kf < 4) ? kf : kf-1; oy = oyv[k]; ox = oxv[k]; av = af[k]; }
        ob[(size_t)(2*kf  )*HWc] = oy;
        ob[(size_t)(2*kf+1)*HWc] = ox;
        ab[(size_t)kf*HWc]       = av;
    }

    float ffv = feat_fix[p];
    buf0[p] = (ffv > 0.f) ? ffv : feat_init[p];
}

// one propagation step, 2 adjacent pixels/thread, float2 tap loads
__global__ __launch_bounds__(256) void prop_step2(
    const float* __restrict__ fin,
    const float* __restrict__ doff,
    const float* __restrict__ daff,
    const float* __restrict__ feat_fix,
    float* __restrict__ out, int apply_mask)
{
    // bijective chunked XCD swizzle (8 XCDs) for gather-line L2 locality
    int nwg = gridDim.x;                       // 1140
    int q = nwg >> 3, r = nwg & 7;
    int xcd = blockIdx.x & 7, pos = blockIdx.x >> 3;
    int sb = (xcd < r ? xcd*(q+1) : r*(q+1) + (xcd - r)*q) + pos;

    int t  = sb*256 + threadIdx.x;             // 0..HALFPIX-1
    int b  = t / (HWc/2);
    int hw = (t - b*(HWc/2)) * 2;              // even pixel index
    int h  = hw / Wc;
    int w  = hw - h*Wc;

    const float* fb = fin  + (size_t)b*HWc;
    const float* ob = doff + (size_t)b*18*HWc + hw;
    const float* ab = daff + (size_t)b*9*HWc  + hw;

    // center tap (kf=4): zero offset -> exact reads
    float2 ar = *(const float2*)(ab + (size_t)4*HWc);
    float s0 = ar.x * fb[hw];
    float s1 = ar.y * fb[hw+1];

    #pragma unroll
    for (int k = 0; k < 8; ++k) {
        int kf = (k < 4) ? k : k+1;
        float2 oy = *(const float2*)(ob + (size_t)(2*kf  )*HWc);
        float2 ox = *(const float2*)(ob + (size_t)(2*kf+1)*HWc);
        float2 a  = *(const float2*)(ab + (size_t)kf*HWc);
        float by = (float)(h + kf/3 - 1);
        float bx = (float)(w + kf%3 - 1);
        s0 += a.x * bilin(fb, by + oy.x, bx + ox.x);
        s1 += a.y * bilin(fb, by + oy.y, bx + 1.f + ox.y);
    }

    int p = b*HWc + hw;
    if (apply_mask) {
        float2 ff = *(const float2*)(feat_fix + p);
        s0 = (ff.x > 0.f) ? ff.x : s0;
        s1 = (ff.y > 0.f) ? ff.y : s1;
    }
    *(float2*)(out + p) = make_float2(s0, s1);
}

extern "C" void kernel_launch(void* const* d_in, const int* in_sizes, int n_in,
                              void* d_out, int out_size, void* d_ws, size_t ws_size,
                              hipStream_t stream) {
    const float* feat_init  = (const float*)d_in[0];
    const float* guidance   = (const float*)d_in[1];
    const float* confidence = (const float*)d_in[2];
    const float* feat_fix   = (const float*)d_in[3];
    const float* w_oa       = (const float*)d_in[4];
    const float* b_oa       = (const float*)d_in[5];
    const float* aff_scale  = (const float*)d_in[6];
    float* out = (float*)d_out;

    float* wsf  = (float*)d_ws;
    float* wr   = wsf + WS_WR;
    float* buf0 = wsf + WS_BUF0;
    float* buf1 = wsf + WS_BUF1;

    reorder_w<<<(24*576 + 255)/256, 256, 0, stream>>>(w_oa, wr);
    conv_epilogue<<<NPIX/256, 256, 0, stream>>>(
        guidance, confidence, wr, b_oa, aff_scale, feat_init, feat_fix, out, buf0);

    const float* doff = out + OUT1;
    const float* daff = out + OUT2;

    float* bufs[2] = {buf0, buf1};
    for (int i = 1; i <= 18; ++i) {
        const float* fi = bufs[(i-1) & 1];
        float* fo = (i == 18) ? out : bufs[i & 1];
        prop_step2<<<HALFPIX/256, 256, 0, stream>>>(fi, doff, daff, feat_fix, fo,
                                                    (i < 18) ? 1 : 0);
    }
}